// Round 5
// baseline (168.747 us; speedup 1.0000x reference)
//
#include <hip/hip_runtime.h>
#include <hip/hip_bf16.h>

// ---- problem constants -------------------------------------------------
#define IN_F   1024
#define OUT_F  1024
#define GS     5          // grid_size
#define SO     3          // spline_order
#define NB     (GS + SO)  // 8 basis functions per feature
#define NG     (GS + 2*SO + 1) // 12 grid points per feature row
#define BATCH  4096
#define KC     (IN_F + IN_F * NB)   // 9216 combined-K
#define BM 256
#define BN 256
#define BK 32
#define SPLITK 4
#define KPART  (KC / SPLITK)   // 2304
#define NT     (KPART / BK)    // 72 K-tiles per block

typedef __bf16 bf16x8 __attribute__((ext_vector_type(8)));
typedef float  f32x4  __attribute__((ext_vector_type(4)));

__device__ __forceinline__ void gload_lds16(const void* g, void* l) {
    __builtin_amdgcn_global_load_lds(
        (const __attribute__((address_space(1))) void*)g,
        (__attribute__((address_space(3))) void*)l,
        16, 0, 0);
}

// ---- build Wc = [base_weight | spline_weight*scaler] in bf16, [OUT_F][KC]
__global__ __launch_bounds__(256) void prep_wc(const float* __restrict__ bw,
                                               const float* __restrict__ sw,
                                               const float* __restrict__ ss,
                                               __bf16* __restrict__ W) {
    const int t = blockIdx.x * 256 + threadIdx.x;
    const int NBASE = OUT_F * IN_F / 8;      // 131072 threads, 8 elems each
    if (t < NBASE) {
        const int o  = t >> 7;
        const int c8 = (t & 127) * 8;
        const float4* sp = (const float4*)(bw + (size_t)o * IN_F + c8);
        float4 v0 = sp[0], v1 = sp[1];
        float v[8] = {v0.x, v0.y, v0.z, v0.w, v1.x, v1.y, v1.z, v1.w};
        bf16x8 ov;
#pragma unroll
        for (int j = 0; j < 8; ++j) ov[j] = (__bf16)v[j];
        *(bf16x8*)(W + (size_t)o * KC + c8) = ov;
    } else {
        const int u = t - NBASE;             // one (o,f) pair per thread
        if (u >= OUT_F * IN_F) return;
        const int o = u >> 10, f = u & 1023;
        const float s = ss[(size_t)o * IN_F + f];
        const float4* sp = (const float4*)(sw + ((size_t)o * IN_F + f) * NB);
        float4 v0 = sp[0], v1 = sp[1];
        float v[8] = {v0.x, v0.y, v0.z, v0.w, v1.x, v1.y, v1.z, v1.w};
        bf16x8 ov;
#pragma unroll
        for (int j = 0; j < 8; ++j) ov[j] = (__bf16)(v[j] * s);
        *(bf16x8*)(W + (size_t)o * KC + IN_F + (size_t)f * NB) = ov;
    }
}

// ---- build A = [silu(x) | b_splines(x)] in bf16, [BATCH][KC] -----------
// Uniform KAN grid -> compile-time knots/denominators, no loads, no divides.
__global__ __launch_bounds__(256) void prep_a(const float* __restrict__ x,
                                              __bf16* __restrict__ A) {
    const int t = blockIdx.x * 256 + threadIdx.x;
    const int NBASE = BATCH * IN_F / 8;      // silu: 8 elems/thread
    if (t < NBASE) {
        const int b  = t >> 7;
        const int c8 = (t & 127) * 8;
        const float4* sp = (const float4*)(x + (size_t)b * IN_F + c8);
        float4 v0 = sp[0], v1 = sp[1];
        float v[8] = {v0.x, v0.y, v0.z, v0.w, v1.x, v1.y, v1.z, v1.w};
        bf16x8 ov;
#pragma unroll
        for (int j = 0; j < 8; ++j) {
            float xx = v[j];
            ov[j] = (__bf16)(xx / (1.0f + __expf(-xx)));
        }
        *(bf16x8*)(A + (size_t)b * KC + c8) = ov;
    } else {
        const int u = t - NBASE;             // one (b,f) pair per thread
        if (u >= BATCH * IN_F) return;
        const int b = u >> 10, f = u & 1023;
        const float xv = x[(size_t)b * IN_F + f];
        const float h = 2.0f / GS;           // 0.4
        float gv[NG];
#pragma unroll
        for (int j = 0; j < NG; ++j) gv[j] = (float)(j - SO) * h - 1.0f;
        float bas[NB + SO];                  // 11 order-0 bases
#pragma unroll
        for (int j = 0; j < NB + SO; ++j)
            bas[j] = (xv >= gv[j] && xv < gv[j + 1]) ? 1.0f : 0.0f;
#pragma unroll
        for (int k = 1; k <= SO; ++k) {
            const float rk = 1.0f / ((float)k * h);   // constant-folded
#pragma unroll
            for (int j = 0; j <= (NB + SO - 1) - k; ++j) {
                float left  = (xv - gv[j]) * rk;
                float right = (gv[j + k + 1] - xv) * rk;
                bas[j] = left * bas[j] + right * bas[j + 1];
            }
        }
        bf16x8 ov;
#pragma unroll
        for (int i = 0; i < NB; ++i) ov[i] = (__bf16)bas[i];
        *(bf16x8*)(A + (size_t)b * KC + IN_F + (size_t)f * NB) = ov;
    }
}

// ---- zero-fill d_out (atomic accumulation target, re-zeroed every call)
__global__ __launch_bounds__(256) void zero_out(float4* __restrict__ p, int n4) {
    const int i = blockIdx.x * 256 + threadIdx.x;
    if (i < n4) p[i] = float4{0.f, 0.f, 0.f, 0.f};
}

// ---- 256x256 split-K GEMM, BK=32, QUAD-buffered LDS, counted vmcnt -----
// Rotation: tile kt lives in buf[kt&3]. At tile kt entry we stage kt+3
// (its buffer's reads retired before the boundary barrier ending kt-1).
// Boundary: vmcnt(8) keeps tiles kt+2,kt+3 in flight -> never drains to 0
// in steady state (T3/T4). T2: slot ^= (row>>1)&3 swizzle -> 2-way (free).
// T5: setprio around clusters.
#define MFMA_CLUSTER(AF, BF, MI0, NI0)                                        \
    __builtin_amdgcn_s_setprio(1);                                            \
    _Pragma("unroll")                                                         \
    for (int i_ = 0; i_ < 4; ++i_)                                            \
        _Pragma("unroll")                                                     \
        for (int n_ = 0; n_ < 2; ++n_)                                        \
            acc[(MI0) + i_][(NI0) + n_] =                                     \
                __builtin_amdgcn_mfma_f32_16x16x32_bf16(                      \
                    AF[i_], BF[n_], acc[(MI0) + i_][(NI0) + n_], 0, 0, 0);    \
    __builtin_amdgcn_s_setprio(0);

#define RD_A(DST, L, ROFF)                                                    \
    _Pragma("unroll")                                                         \
    for (int i_ = 0; i_ < 4; ++i_)                                            \
        DST[i_] = *(const bf16x8*)&(L)[aBase + (ROFF) + i_ * 512 + slotRd];

#define RD_B(DST, L, ROFF)                                                    \
    _Pragma("unroll")                                                         \
    for (int n_ = 0; n_ < 2; ++n_)                                            \
        DST[n_] = *(const bf16x8*)&(L)[bBase + (ROFF) + n_ * 512 + slotRd];

__global__ __launch_bounds__(512, 2) void kan_gemm(const __bf16* __restrict__ A,
                                                   const __bf16* __restrict__ W,
                                                   float* __restrict__ C) {
    __shared__ __bf16 sA[4][BM * BK];   // 4 x 16 KiB
    __shared__ __bf16 sB[4][BN * BK];   // 4 x 16 KiB

    const int tid  = threadIdx.x;
    const int gid  = blockIdx.x;
    // bijective XCD swizzle (256 = 8*32): XCD x owns one ks, two bn panels.
    const int work = (gid & 7) * 32 + (gid >> 3);
    const int ks = work >> 6;          // 0..3
    const int bn = (work >> 4) & 3;    // 0..3
    const int bm = work & 15;          // 0..15

    const int lane = tid & 63;
    const int wv   = tid >> 6;         // 0..7
    const int wm   = wv >> 2;          // 0..1  (M half)
    const int wn   = wv & 3;           // 0..3  (N quarter)
    const int lr   = lane & 15;        // fragment row
    const int hi   = lane >> 4;        // 0..3 -> k-subslot (k = hi*8..hi*8+7)

    // swizzle key for ds_read: fragment rows are base(mult of 16)+lr, so
    // (row>>1)&3 == (lr>>1)&3 -> lane-uniform constant.
    const int slotRd = ((hi ^ ((lr >> 1) & 3)) << 3);
    const int aBase  = (wm * 128 + lr) * 32;
    const int bBase  = (wn * 64 + lr) * 32;

    const __bf16* gA = A + (size_t)(bm * BM) * KC + ks * KPART;
    const __bf16* gW = W + (size_t)(bn * BN) * KC + ks * KPART;

    f32x4 acc[8][4] = {};
    bf16x8 a0[4], a1[4], b01[2], b23[2];

    auto stage = [&](int buf, int kt) {
        const int koff = kt * BK;
#pragma unroll
        for (int r = 0; r < 2; ++r) {
            const int chunk = r * 512 + tid;          // 16B chunk (1024/matrix)
            const int row = chunk >> 2, slot = chunk & 3;
            const int col = (slot ^ ((row >> 1) & 3)) << 3;
            gload_lds16(gA + (size_t)row * KC + koff + col,
                        &sA[buf][chunk * 8]);         // linear LDS dest
        }
#pragma unroll
        for (int r = 0; r < 2; ++r) {
            const int chunk = r * 512 + tid;
            const int row = chunk >> 2, slot = chunk & 3;
            const int col = (slot ^ ((row >> 1) & 3)) << 3;
            gload_lds16(gW + (size_t)row * KC + koff + col,
                        &sB[buf][chunk * 8]);
        }
    };

    // prologue: stage tiles 0,1,2 (12 loads); wait tile0 only (vmcnt 8)
    stage(0, 0);
    stage(1, 1);
    stage(2, 2);
    asm volatile("s_waitcnt vmcnt(8)\n\ts_barrier" ::: "memory");
    RD_A(a0, &sA[0][0], 0);
    RD_B(b01, &sB[0][0], 0);

    for (int kt = 0; kt < NT; ++kt) {
        const int rb = kt & 3;
        const __bf16* LA = &sA[rb][0];
        const __bf16* LB = &sB[rb][0];

        // stage tile kt+3 into buf[(kt+3)&3] (reads of that buffer retired
        // before the boundary barrier that ended tile kt-1)
        if (kt + 3 < NT) stage((kt + 3) & 3, kt + 3);

        RD_B(b23, LB, 1024);                 // rows +32..63
        MFMA_CLUSTER(a0, b01, 0, 0);
        RD_A(a1, LA, 2048);                  // rows +64..127
        MFMA_CLUSTER(a0, b23, 0, 2);
        MFMA_CLUSTER(a1, b01, 4, 0);

        if (kt + 1 < NT) {
            // boundary: all this buffer's ds_reads are lgkm-retired by the
            // clusters above; counted wait -> tiles kt+2,kt+3 stay in flight
            if (kt + 3 < NT)
                asm volatile("s_waitcnt vmcnt(8)\n\ts_barrier" ::: "memory");
            else if (kt + 2 < NT)
                asm volatile("s_waitcnt vmcnt(4)\n\ts_barrier" ::: "memory");
            else
                asm volatile("s_waitcnt vmcnt(0)\n\ts_barrier" ::: "memory");
            const int rn = (kt + 1) & 3;
            RD_A(a0, &sA[rn][0], 0);          // pre-read next tile,
            RD_B(b01, &sB[rn][0], 0);         // overlapped with last cluster
        }
        MFMA_CLUSTER(a1, b23, 4, 2);
    }

    // epilogue: C/D layout col=lane&15, row=(lane>>4)*4+reg; fp32 hw atomics
    const int cr = hi * 4, cc = lane & 15;
#pragma unroll
    for (int mi = 0; mi < 8; ++mi)
#pragma unroll
        for (int ni = 0; ni < 4; ++ni) {
            float* cp = C + (size_t)(bm * BM + wm * 128 + mi * 16 + cr) * OUT_F
                          + bn * BN + wn * 64 + ni * 16 + cc;
#pragma unroll
            for (int r = 0; r < 4; ++r)
                unsafeAtomicAdd(cp + (size_t)r * OUT_F, acc[mi][ni][r]);
        }
}

extern "C" void kernel_launch(void* const* d_in, const int* in_sizes, int n_in,
                              void* d_out, int out_size, void* d_ws, size_t ws_size,
                              hipStream_t stream) {
    const float* x    = (const float*)d_in[0];
    const float* bw   = (const float*)d_in[1];
    const float* sw   = (const float*)d_in[2];
    const float* ss   = (const float*)d_in[3];

    const size_t wc_bytes = (size_t)OUT_F * KC * 2;   // 18,874,368
    const size_t a_bytes  = (size_t)BATCH * KC * 2;   // 75,497,472
    if (ws_size < wc_bytes + a_bytes) return;

    __bf16* Wc = (__bf16*)d_ws;
    __bf16* A  = (__bf16*)((char*)d_ws + wc_bytes);

    {   // Wc: 131072 + 1048576 threads
        const int total = OUT_F * IN_F / 8 + OUT_F * IN_F;
        prep_wc<<<(total + 255) / 256, 256, 0, stream>>>(bw, sw, ss, Wc);
    }
    {   // A: 524288 + 4194304 threads
        const int total = BATCH * IN_F / 8 + BATCH * IN_F;
        prep_a<<<(total + 255) / 256, 256, 0, stream>>>(x, A);
    }
    {   // zero d_out (atomic target; must be re-zeroed every call)
        const int n4 = BATCH * OUT_F / 4;
        zero_out<<<n4 / 256, 256, 0, stream>>>((float4*)d_out, n4);
    }
    kan_gemm<<<(BATCH / BM) * (OUT_F / BN) * SPLITK, 512, 0, stream>>>(A, Wc, (float*)d_out);
}

// Round 6
// 150.303 us; speedup vs baseline: 1.1227x; 1.1227x over previous
//
#include <hip/hip_runtime.h>
#include <hip/hip_bf16.h>

// ---- problem constants -------------------------------------------------
#define IN_F   1024
#define OUT_F  1024
#define GS     5          // grid_size
#define SO     3          // spline_order
#define NB     (GS + SO)  // 8 basis functions per feature
#define NG     (GS + 2*SO + 1) // 12 grid points per feature row
#define BATCH  4096
#define KC     (IN_F + IN_F * NB)   // 9216 combined-K
#define BM 256
#define BN 256
#define BK 64
#define SPLITK 4
#define KPART  (KC / SPLITK)   // 2304
#define NT     (KPART / BK)    // 36 K-tiles per block

typedef __bf16 bf16x8 __attribute__((ext_vector_type(8)));
typedef float  f32x4  __attribute__((ext_vector_type(4)));

__device__ __forceinline__ void gload_lds16(const void* g, void* l) {
    __builtin_amdgcn_global_load_lds(
        (const __attribute__((address_space(1))) void*)g,
        (__attribute__((address_space(3))) void*)l,
        16, 0, 0);
}

// ---- build Wc = [base_weight | spline_weight*scaler] in bf16, [OUT_F][KC]
__global__ __launch_bounds__(256) void prep_wc(const float* __restrict__ bw,
                                               const float* __restrict__ sw,
                                               const float* __restrict__ ss,
                                               __bf16* __restrict__ W) {
    const int t = blockIdx.x * 256 + threadIdx.x;
    const int NBASE = OUT_F * IN_F / 8;      // 131072 threads, 8 elems each
    if (t < NBASE) {
        const int o  = t >> 7;
        const int c8 = (t & 127) * 8;
        const float4* sp = (const float4*)(bw + (size_t)o * IN_F + c8);
        float4 v0 = sp[0], v1 = sp[1];
        float v[8] = {v0.x, v0.y, v0.z, v0.w, v1.x, v1.y, v1.z, v1.w};
        bf16x8 ov;
#pragma unroll
        for (int j = 0; j < 8; ++j) ov[j] = (__bf16)v[j];
        *(bf16x8*)(W + (size_t)o * KC + c8) = ov;
    } else {
        const int u = t - NBASE;             // one (o,f) pair per thread
        if (u >= OUT_F * IN_F) return;
        const int o = u >> 10, f = u & 1023;
        const float s = ss[(size_t)o * IN_F + f];
        const float4* sp = (const float4*)(sw + ((size_t)o * IN_F + f) * NB);
        float4 v0 = sp[0], v1 = sp[1];
        float v[8] = {v0.x, v0.y, v0.z, v0.w, v1.x, v1.y, v1.z, v1.w};
        bf16x8 ov;
#pragma unroll
        for (int j = 0; j < 8; ++j) ov[j] = (__bf16)(v[j] * s);
        *(bf16x8*)(W + (size_t)o * KC + IN_F + (size_t)f * NB) = ov;
    }
}

// ---- build A = [silu(x) | b_splines(x)] in bf16, [BATCH][KC] -----------
__global__ __launch_bounds__(256) void prep_a(const float* __restrict__ x,
                                              __bf16* __restrict__ A) {
    const int t = blockIdx.x * 256 + threadIdx.x;
    const int NBASE = BATCH * IN_F / 8;      // silu: 8 elems/thread
    if (t < NBASE) {
        const int b  = t >> 7;
        const int c8 = (t & 127) * 8;
        const float4* sp = (const float4*)(x + (size_t)b * IN_F + c8);
        float4 v0 = sp[0], v1 = sp[1];
        float v[8] = {v0.x, v0.y, v0.z, v0.w, v1.x, v1.y, v1.z, v1.w};
        bf16x8 ov;
#pragma unroll
        for (int j = 0; j < 8; ++j) {
            float xx = v[j];
            ov[j] = (__bf16)(xx / (1.0f + __expf(-xx)));
        }
        *(bf16x8*)(A + (size_t)b * KC + c8) = ov;
    } else {
        const int u = t - NBASE;             // one (b,f) pair per thread
        if (u >= BATCH * IN_F) return;
        const int b = u >> 10, f = u & 1023;
        const float xv = x[(size_t)b * IN_F + f];
        const float h = 2.0f / GS;           // 0.4
        float gv[NG];
#pragma unroll
        for (int j = 0; j < NG; ++j) gv[j] = (float)(j - SO) * h - 1.0f;
        float bas[NB + SO];                  // 11 order-0 bases
#pragma unroll
        for (int j = 0; j < NB + SO; ++j)
            bas[j] = (xv >= gv[j] && xv < gv[j + 1]) ? 1.0f : 0.0f;
#pragma unroll
        for (int k = 1; k <= SO; ++k) {
            const float rk = 1.0f / ((float)k * h);   // constant-folded
#pragma unroll
            for (int j = 0; j <= (NB + SO - 1) - k; ++j) {
                float left  = (xv - gv[j]) * rk;
                float right = (gv[j + k + 1] - xv) * rk;
                bas[j] = left * bas[j] + right * bas[j + 1];
            }
        }
        bf16x8 ov;
#pragma unroll
        for (int i = 0; i < NB; ++i) ov[i] = (__bf16)bas[i];
        *(bf16x8*)(A + (size_t)b * KC + IN_F + (size_t)f * NB) = ov;
    }
}

// ---- zero-fill d_out (atomic accumulation target, re-zeroed every call)
__global__ __launch_bounds__(256) void zero_out(float4* __restrict__ p, int n4) {
    const int i = blockIdx.x * 256 + threadIdx.x;
    if (i < n4) p[i] = float4{0.f, 0.f, 0.f, 0.f};
}

// ---- m201-style 8-phase 256x256 GEMM (4 phases/K-tile), split-K --------
// Per phase: {ds_read subtile | stage 1-2 half-tiles -> barrier ->
// lgkmcnt(0) -> setprio(1) 16 MFMA setprio(0) -> barrier}. Counted
// vmcnt(6) once per K-tile (3 half-tiles in flight, never 0 mid-loop).
// Half-tile staging stream during tile T: [T+1.B1 | T+2.B0 | T+2.A0+A1];
// WAR-safe: each region's tile-T reads retired a barrier earlier.
#define PH_SYNC do { __builtin_amdgcn_s_barrier();                            \
    asm volatile("s_waitcnt lgkmcnt(0)" ::: "memory");                        \
    __builtin_amdgcn_sched_barrier(0); } while (0)

#define MFMA16(AF, BF, MI0, NI0)                                              \
    __builtin_amdgcn_s_setprio(1);                                            \
    _Pragma("unroll")                                                         \
    for (int kk_ = 0; kk_ < 2; ++kk_)                                         \
        _Pragma("unroll")                                                     \
        for (int i_ = 0; i_ < 4; ++i_)                                        \
            _Pragma("unroll")                                                 \
            for (int n_ = 0; n_ < 2; ++n_)                                    \
                acc[(MI0) + i_][(NI0) + n_] =                                 \
                    __builtin_amdgcn_mfma_f32_16x16x32_bf16(                  \
                        AF[i_][kk_], BF[n_][kk_],                             \
                        acc[(MI0) + i_][(NI0) + n_], 0, 0, 0);                \
    __builtin_amdgcn_s_setprio(0);                                            \
    __builtin_amdgcn_s_barrier();

#define RD_A4(DST, LBUF, MI0)                                                 \
    _Pragma("unroll")                                                         \
    for (int i_ = 0; i_ < 4; ++i_) {                                          \
        DST[i_][0] = *(const bf16x8*)&(LBUF)[((MI0) + i_) * 1024 + aRow + slot0]; \
        DST[i_][1] = *(const bf16x8*)&(LBUF)[((MI0) + i_) * 1024 + aRow + slot1]; \
    }

#define RD_B2(DST, LBUF, NI0)                                                 \
    _Pragma("unroll")                                                         \
    for (int n_ = 0; n_ < 2; ++n_) {                                          \
        DST[n_][0] = *(const bf16x8*)&(LBUF)[bRow + ((NI0) + n_) * 1024 + slot0]; \
        DST[n_][1] = *(const bf16x8*)&(LBUF)[bRow + ((NI0) + n_) * 1024 + slot1]; \
    }

__global__ __launch_bounds__(512, 2) void kan_gemm(const __bf16* __restrict__ A,
                                                   const __bf16* __restrict__ W,
                                                   float* __restrict__ C) {
    __shared__ __bf16 sA[2][2][128 * BK];   // [buf][half][128x64] = 64 KiB
    __shared__ __bf16 sB[2][2][128 * BK];   // 64 KiB

    const int tid  = threadIdx.x;
    const int gid  = blockIdx.x;
    // bijective XCD swizzle (256 = 8*32): XCD x owns one ks, two bn panels.
    const int work = (gid & 7) * 32 + (gid >> 3);
    const int ks = work >> 6;          // 0..3
    const int bn = (work >> 4) & 3;    // 0..3
    const int bm = work & 15;          // 0..15

    const int lane = tid & 63;
    const int wv   = tid >> 6;         // 0..7
    const int wm   = wv >> 2;          // 0..1: A half
    const int wn   = wv & 3;           // 0..3: B half = wn>>1, sub = wn&1
    const int lr   = lane & 15;        // fragment row
    const int hi   = lane >> 4;        // 0..3: k-subslot
    const int key  = lr & 7;           // swizzle key (frag rows = 16*m + lr)

    const int slot0 = ((hi ^ key) << 3);        // kk=0: 16B slot 0..3
    const int slot1 = (((4 + hi) ^ key) << 3);  // kk=1: slot 4..7
    const int aRow  = lr * 64;                  // within sA[b][wm]
    const int bRow  = ((wn & 1) * 64 + lr) * 64;// within sB[b][wn>>1]

    // staging map: thread -> (row, swizzled col) for each half-tile
    const int srow = tid >> 3;                       // 0..63
    const int scol = ((tid & 7) ^ (srow & 7)) << 3;  // elems

    const __bf16* gA = A + (size_t)(bm * BM) * KC + ks * KPART;
    const __bf16* gW = W + (size_t)(bn * BN) * KC + ks * KPART;

    f32x4 acc[8][4] = {};
    bf16x8 af[4][2], b01[2][2], b23[2][2];

    auto stageA = [&](int buf, int h, int kt) {      // one 16 KiB half-tile
#pragma unroll
        for (int l = 0; l < 2; ++l)
            gload_lds16(gA + (size_t)(h * 128 + l * 64 + srow) * KC + kt * BK + scol,
                        &sA[buf][h][(l * 512 + tid) * 8]);
    };
    auto stageB = [&](int buf, int h, int kt) {
#pragma unroll
        for (int l = 0; l < 2; ++l)
            gload_lds16(gW + (size_t)(h * 128 + l * 64 + srow) * KC + kt * BK + scol,
                        &sB[buf][h][(l * 512 + tid) * 8]);
    };

    // prologue: tile0 fully (8 loads) + tile1 A0,A1,B0 (6 loads)
    stageA(0, 0, 0); stageA(0, 1, 0); stageB(0, 0, 0); stageB(0, 1, 0);
    stageA(1, 0, 1); stageA(1, 1, 1); stageB(1, 0, 1);
    asm volatile("s_waitcnt vmcnt(6)\n\ts_barrier" ::: "memory");

    for (int kt = 0; kt < NT; ++kt) {
        const int b = kt & 1;
        const __bf16* LA = &sA[b][wm][0];
        const __bf16* LB = &sB[b][wn >> 1][0];

        // ---- Ph1: read A mi0-3 (8) + B ni0-1 (4); MFMA Q1
        RD_A4(af, LA, 0);
        RD_B2(b01, LB, 0);
        PH_SYNC;
        MFMA16(af, b01, 0, 0);

        // ---- Ph2: read B ni2-3 (4); stage (kt+1).B1; MFMA Q2
        RD_B2(b23, LB, 2);
        if (kt + 1 < NT) stageB(b ^ 1, 1, kt + 1);
        PH_SYNC;
        MFMA16(af, b23, 0, 2);

        // ---- Ph3: read A mi4-7 (8); stage (kt+2).B0; MFMA Q3
        // (tile kt's B reads all retired before Ph2's trailing barrier)
        RD_A4(af, LA, 4);
        if (kt + 2 < NT) stageB(b, 0, kt + 2);
        PH_SYNC;
        MFMA16(af, b01, 4, 0);

        // ---- Ph4: stage (kt+2).A0,A1; MFMA Q4
        // (tile kt's A reads all retired before Ph3's trailing barrier)
        if (kt + 2 < NT) { stageA(b, 0, kt + 2); stageA(b, 1, kt + 2); }
        __builtin_amdgcn_s_barrier();
        __builtin_amdgcn_s_setprio(1);
#pragma unroll
        for (int kk_ = 0; kk_ < 2; ++kk_)
#pragma unroll
            for (int i_ = 0; i_ < 4; ++i_)
#pragma unroll
                for (int n_ = 0; n_ < 2; ++n_)
                    acc[4 + i_][2 + n_] = __builtin_amdgcn_mfma_f32_16x16x32_bf16(
                        af[i_][kk_], b23[n_][kk_], acc[4 + i_][2 + n_], 0, 0, 0);
        __builtin_amdgcn_s_setprio(0);

        // ---- boundary: counted wait; newest 6 loads = (kt+2).{B0,A0,A1}
        // -> everything through (kt+1).B1 complete; tile kt+1 resident.
        if (kt + 2 < NT)
            asm volatile("s_waitcnt vmcnt(6)\n\ts_barrier" ::: "memory");
        else if (kt + 1 < NT)
            asm volatile("s_waitcnt vmcnt(0)\n\ts_barrier" ::: "memory");
    }

    // epilogue: C/D layout col=lane&15, row=hi*4+reg; fp32 hw atomics
    const int cr = hi * 4, cc = lane & 15;
#pragma unroll
    for (int mi = 0; mi < 8; ++mi)
#pragma unroll
        for (int ni = 0; ni < 4; ++ni) {
            float* cp = C + (size_t)(bm * BM + wm * 128 + mi * 16 + cr) * OUT_F
                          + bn * BN + wn * 64 + ni * 16 + cc;
#pragma unroll
            for (int r = 0; r < 4; ++r)
                unsafeAtomicAdd(cp + (size_t)r * OUT_F, acc[mi][ni][r]);
        }
}

extern "C" void kernel_launch(void* const* d_in, const int* in_sizes, int n_in,
                              void* d_out, int out_size, void* d_ws, size_t ws_size,
                              hipStream_t stream) {
    const float* x    = (const float*)d_in[0];
    const float* bw   = (const float*)d_in[1];
    const float* sw   = (const float*)d_in[2];
    const float* ss   = (const float*)d_in[3];

    const size_t wc_bytes = (size_t)OUT_F * KC * 2;   // 18,874,368
    const size_t a_bytes  = (size_t)BATCH * KC * 2;   // 75,497,472
    if (ws_size < wc_bytes + a_bytes) return;

    __bf16* Wc = (__bf16*)d_ws;
    __bf16* A  = (__bf16*)((char*)d_ws + wc_bytes);

    {   // Wc: 131072 + 1048576 threads
        const int total = OUT_F * IN_F / 8 + OUT_F * IN_F;
        prep_wc<<<(total + 255) / 256, 256, 0, stream>>>(bw, sw, ss, Wc);
    }
    {   // A: 524288 + 4194304 threads
        const int total = BATCH * IN_F / 8 + BATCH * IN_F;
        prep_a<<<(total + 255) / 256, 256, 0, stream>>>(x, A);
    }
    {   // zero d_out (atomic target; must be re-zeroed every call)
        const int n4 = BATCH * OUT_F / 4;
        zero_out<<<n4 / 256, 256, 0, stream>>>((float4*)d_out, n4);
    }
    kan_gemm<<<(BATCH / BM) * (OUT_F / BN) * SPLITK, 512, 0, stream>>>(A, Wc, (float*)d_out);
}

// Round 7
// 118.620 us; speedup vs baseline: 1.4226x; 1.2671x over previous
//
#include <hip/hip_runtime.h>
#include <hip/hip_bf16.h>

// ---- problem constants -------------------------------------------------
#define IN_F   1024
#define OUT_F  1024
#define GS     5          // grid_size
#define SO     3          // spline_order
#define NB     (GS + SO)  // 8 basis functions per feature
#define NG     (GS + 2*SO + 1) // 12 grid points per feature row
#define BATCH  4096
#define KC     (IN_F + IN_F * NB)   // 9216 combined-K
#define BM 256
#define BN 256
#define BK 64
#define SPLITK 4
#define KPART  (KC / SPLITK)   // 2304
#define NT     (KPART / BK)    // 36 K-tiles per block

typedef __bf16 bf16x8 __attribute__((ext_vector_type(8)));
typedef float  f32x4  __attribute__((ext_vector_type(4)));

__device__ __forceinline__ void gload_lds16(const void* g, void* l) {
    __builtin_amdgcn_global_load_lds(
        (const __attribute__((address_space(1))) void*)g,
        (__attribute__((address_space(3))) void*)l,
        16, 0, 0);
}

// ---- build Wc = [base_weight | spline_weight*scaler] in bf16, [OUT_F][KC]
__global__ __launch_bounds__(256) void prep_wc(const float* __restrict__ bw,
                                               const float* __restrict__ sw,
                                               const float* __restrict__ ss,
                                               __bf16* __restrict__ W) {
    const int t = blockIdx.x * 256 + threadIdx.x;
    const int NBASE = OUT_F * IN_F / 8;      // 131072 threads, 8 elems each
    if (t < NBASE) {
        const int o  = t >> 7;
        const int c8 = (t & 127) * 8;
        const float4* sp = (const float4*)(bw + (size_t)o * IN_F + c8);
        float4 v0 = sp[0], v1 = sp[1];
        float v[8] = {v0.x, v0.y, v0.z, v0.w, v1.x, v1.y, v1.z, v1.w};
        bf16x8 ov;
#pragma unroll
        for (int j = 0; j < 8; ++j) ov[j] = (__bf16)v[j];
        *(bf16x8*)(W + (size_t)o * KC + c8) = ov;
    } else {
        const int u = t - NBASE;             // one (o,f) pair per thread
        if (u >= OUT_F * IN_F) return;
        const int o = u >> 10, f = u & 1023;
        const float s = ss[(size_t)o * IN_F + f];
        const float4* sp = (const float4*)(sw + ((size_t)o * IN_F + f) * NB);
        float4 v0 = sp[0], v1 = sp[1];
        float v[8] = {v0.x, v0.y, v0.z, v0.w, v1.x, v1.y, v1.z, v1.w};
        bf16x8 ov;
#pragma unroll
        for (int j = 0; j < 8; ++j) ov[j] = (__bf16)(v[j] * s);
        *(bf16x8*)(W + (size_t)o * KC + IN_F + (size_t)f * NB) = ov;
    }
}

// ---- build A = [silu(x) | b_splines(x)] in bf16, [BATCH][KC] -----------
__global__ __launch_bounds__(256) void prep_a(const float* __restrict__ x,
                                              __bf16* __restrict__ A) {
    const int t = blockIdx.x * 256 + threadIdx.x;
    const int NBASE = BATCH * IN_F / 8;      // silu: 8 elems/thread
    if (t < NBASE) {
        const int b  = t >> 7;
        const int c8 = (t & 127) * 8;
        const float4* sp = (const float4*)(x + (size_t)b * IN_F + c8);
        float4 v0 = sp[0], v1 = sp[1];
        float v[8] = {v0.x, v0.y, v0.z, v0.w, v1.x, v1.y, v1.z, v1.w};
        bf16x8 ov;
#pragma unroll
        for (int j = 0; j < 8; ++j) {
            float xx = v[j];
            ov[j] = (__bf16)(xx / (1.0f + __expf(-xx)));
        }
        *(bf16x8*)(A + (size_t)b * KC + c8) = ov;
    } else {
        const int u = t - NBASE;             // one (b,f) pair per thread
        if (u >= BATCH * IN_F) return;
        const int b = u >> 10, f = u & 1023;
        const float xv = x[(size_t)b * IN_F + f];
        const float h = 2.0f / GS;           // 0.4
        float gv[NG];
#pragma unroll
        for (int j = 0; j < NG; ++j) gv[j] = (float)(j - SO) * h - 1.0f;
        float bas[NB + SO];                  // 11 order-0 bases
#pragma unroll
        for (int j = 0; j < NB + SO; ++j)
            bas[j] = (xv >= gv[j] && xv < gv[j + 1]) ? 1.0f : 0.0f;
#pragma unroll
        for (int k = 1; k <= SO; ++k) {
            const float rk = 1.0f / ((float)k * h);   // constant-folded
#pragma unroll
            for (int j = 0; j <= (NB + SO - 1) - k; ++j) {
                float left  = (xv - gv[j]) * rk;
                float right = (gv[j + k + 1] - xv) * rk;
                bas[j] = left * bas[j] + right * bas[j + 1];
            }
        }
        bf16x8 ov;
#pragma unroll
        for (int i = 0; i < NB; ++i) ov[i] = (__bf16)bas[i];
        *(bf16x8*)(A + (size_t)b * KC + IN_F + (size_t)f * NB) = ov;
    }
}

// ---- zero-fill d_out (atomic-fallback path only) -----------------------
__global__ __launch_bounds__(256) void zero_out(float4* __restrict__ p, int n4) {
    const int i = blockIdx.x * 256 + threadIdx.x;
    if (i < n4) p[i] = float4{0.f, 0.f, 0.f, 0.f};
}

// ---- sum split-K partials into d_out (ks=0 wrote d_out directly) -------
__global__ __launch_bounds__(256) void reduce_k(float4* __restrict__ C,
                                                const float4* __restrict__ P) {
    const size_t n4 = (size_t)BATCH * OUT_F / 4;   // 1,048,576
    for (size_t i = blockIdx.x * 256 + threadIdx.x; i < n4; i += 2048 * 256) {
        float4 c  = C[i];
        float4 p0 = P[i];
        float4 p1 = P[n4 + i];
        float4 p2 = P[2 * n4 + i];
        c.x += p0.x + p1.x + p2.x;
        c.y += p0.y + p1.y + p2.y;
        c.z += p0.z + p1.z + p2.z;
        c.w += p0.w + p1.w + p2.w;
        C[i] = c;
    }
}

// ---- m201-style 4-phase/K-tile 256x256 GEMM, split-K -------------------
// K-loop identical to r6 (staging placement is the unique WAR-safe one).
// Epilogue templated: ATOMIC=false -> ks0 stores d_out, ks1-3 store
// partials (plain coalesced-line scatter stores, no RMW); ATOMIC=true ->
// r6 behavior (fallback when ws too small).
#define PH_SYNC do { __builtin_amdgcn_s_barrier();                            \
    asm volatile("s_waitcnt lgkmcnt(0)" ::: "memory");                        \
    __builtin_amdgcn_sched_barrier(0); } while (0)

#define MFMA16(AF, BF, MI0, NI0)                                              \
    __builtin_amdgcn_s_setprio(1);                                            \
    _Pragma("unroll")                                                         \
    for (int kk_ = 0; kk_ < 2; ++kk_)                                         \
        _Pragma("unroll")                                                     \
        for (int i_ = 0; i_ < 4; ++i_)                                        \
            _Pragma("unroll")                                                 \
            for (int n_ = 0; n_ < 2; ++n_)                                    \
                acc[(MI0) + i_][(NI0) + n_] =                                 \
                    __builtin_amdgcn_mfma_f32_16x16x32_bf16(                  \
                        AF[i_][kk_], BF[n_][kk_],                             \
                        acc[(MI0) + i_][(NI0) + n_], 0, 0, 0);                \
    __builtin_amdgcn_s_setprio(0);                                            \
    __builtin_amdgcn_s_barrier();

#define RD_A4(DST, LBUF, MI0)                                                 \
    _Pragma("unroll")                                                         \
    for (int i_ = 0; i_ < 4; ++i_) {                                          \
        DST[i_][0] = *(const bf16x8*)&(LBUF)[((MI0) + i_) * 1024 + aRow + slot0]; \
        DST[i_][1] = *(const bf16x8*)&(LBUF)[((MI0) + i_) * 1024 + aRow + slot1]; \
    }

#define RD_B2(DST, LBUF, NI0)                                                 \
    _Pragma("unroll")                                                         \
    for (int n_ = 0; n_ < 2; ++n_) {                                          \
        DST[n_][0] = *(const bf16x8*)&(LBUF)[bRow + ((NI0) + n_) * 1024 + slot0]; \
        DST[n_][1] = *(const bf16x8*)&(LBUF)[bRow + ((NI0) + n_) * 1024 + slot1]; \
    }

template<bool ATOMIC>
__global__ __launch_bounds__(512, 2) void kan_gemm(const __bf16* __restrict__ A,
                                                   const __bf16* __restrict__ W,
                                                   float* __restrict__ C,
                                                   float* __restrict__ P) {
    __shared__ __bf16 sA[2][2][128 * BK];   // [buf][half][128x64] = 64 KiB
    __shared__ __bf16 sB[2][2][128 * BK];   // 64 KiB

    const int tid  = threadIdx.x;
    const int gid  = blockIdx.x;
    // bijective XCD swizzle (256 = 8*32): XCD x owns one ks, two bn panels.
    const int work = (gid & 7) * 32 + (gid >> 3);
    const int ks = work >> 6;          // 0..3
    const int bn = (work >> 4) & 3;    // 0..3
    const int bm = work & 15;          // 0..15

    const int lane = tid & 63;
    const int wv   = tid >> 6;         // 0..7
    const int wm   = wv >> 2;          // 0..1: A half
    const int wn   = wv & 3;           // 0..3: B half = wn>>1, sub = wn&1
    const int lr   = lane & 15;        // fragment row
    const int hi   = lane >> 4;        // 0..3: k-subslot
    const int key  = lr & 7;           // swizzle key (frag rows = 16*m + lr)

    const int slot0 = ((hi ^ key) << 3);        // kk=0: 16B slot 0..3
    const int slot1 = (((4 + hi) ^ key) << 3);  // kk=1: slot 4..7
    const int aRow  = lr * 64;                  // within sA[b][wm]
    const int bRow  = ((wn & 1) * 64 + lr) * 64;// within sB[b][wn>>1]

    // staging map: thread -> (row, swizzled col) for each half-tile
    const int srow = tid >> 3;                       // 0..63
    const int scol = ((tid & 7) ^ (srow & 7)) << 3;  // elems

    const __bf16* gA = A + (size_t)(bm * BM) * KC + ks * KPART;
    const __bf16* gW = W + (size_t)(bn * BN) * KC + ks * KPART;

    f32x4 acc[8][4] = {};
    bf16x8 af[4][2], b01[2][2], b23[2][2];

    auto stageA = [&](int buf, int h, int kt) {      // one 16 KiB half-tile
#pragma unroll
        for (int l = 0; l < 2; ++l)
            gload_lds16(gA + (size_t)(h * 128 + l * 64 + srow) * KC + kt * BK + scol,
                        &sA[buf][h][(l * 512 + tid) * 8]);
    };
    auto stageB = [&](int buf, int h, int kt) {
#pragma unroll
        for (int l = 0; l < 2; ++l)
            gload_lds16(gW + (size_t)(h * 128 + l * 64 + srow) * KC + kt * BK + scol,
                        &sB[buf][h][(l * 512 + tid) * 8]);
    };

    // prologue: tile0 fully (8 loads) + tile1 A0,A1,B0 (6 loads)
    stageA(0, 0, 0); stageA(0, 1, 0); stageB(0, 0, 0); stageB(0, 1, 0);
    stageA(1, 0, 1); stageA(1, 1, 1); stageB(1, 0, 1);
    asm volatile("s_waitcnt vmcnt(6)\n\ts_barrier" ::: "memory");

    for (int kt = 0; kt < NT; ++kt) {
        const int b = kt & 1;
        const __bf16* LA = &sA[b][wm][0];
        const __bf16* LB = &sB[b][wn >> 1][0];

        // ---- Ph1: read A mi0-3 (8) + B ni0-1 (4); MFMA Q1
        RD_A4(af, LA, 0);
        RD_B2(b01, LB, 0);
        PH_SYNC;
        MFMA16(af, b01, 0, 0);

        // ---- Ph2: read B ni2-3 (4); stage (kt+1).B1; MFMA Q2
        RD_B2(b23, LB, 2);
        if (kt + 1 < NT) stageB(b ^ 1, 1, kt + 1);
        PH_SYNC;
        MFMA16(af, b23, 0, 2);

        // ---- Ph3: read A mi4-7 (8); stage (kt+2).B0; MFMA Q3
        RD_A4(af, LA, 4);
        if (kt + 2 < NT) stageB(b, 0, kt + 2);
        PH_SYNC;
        MFMA16(af, b01, 4, 0);

        // ---- Ph4: stage (kt+2).A0,A1; MFMA Q4
        if (kt + 2 < NT) { stageA(b, 0, kt + 2); stageA(b, 1, kt + 2); }
        __builtin_amdgcn_s_barrier();
        __builtin_amdgcn_s_setprio(1);
#pragma unroll
        for (int kk_ = 0; kk_ < 2; ++kk_)
#pragma unroll
            for (int i_ = 0; i_ < 4; ++i_)
#pragma unroll
                for (int n_ = 0; n_ < 2; ++n_)
                    acc[4 + i_][2 + n_] = __builtin_amdgcn_mfma_f32_16x16x32_bf16(
                        af[i_][kk_], b23[n_][kk_], acc[4 + i_][2 + n_], 0, 0, 0);
        __builtin_amdgcn_s_setprio(0);

        // ---- boundary: counted wait (tiles kt+2 stay in flight)
        if (kt + 2 < NT)
            asm volatile("s_waitcnt vmcnt(6)\n\ts_barrier" ::: "memory");
        else if (kt + 1 < NT)
            asm volatile("s_waitcnt vmcnt(0)\n\ts_barrier" ::: "memory");
    }

    // epilogue: C/D layout col=lane&15, row=hi*4+reg
    const int cr = hi * 4, cc = lane & 15;
    float* dst;
    if (ATOMIC) dst = C;
    else        dst = (ks == 0) ? C : P + (size_t)(ks - 1) * BATCH * OUT_F;
#pragma unroll
    for (int mi = 0; mi < 8; ++mi)
#pragma unroll
        for (int ni = 0; ni < 4; ++ni) {
            float* cp = dst + (size_t)(bm * BM + wm * 128 + mi * 16 + cr) * OUT_F
                            + bn * BN + wn * 64 + ni * 16 + cc;
#pragma unroll
            for (int r = 0; r < 4; ++r) {
                if (ATOMIC) unsafeAtomicAdd(cp + (size_t)r * OUT_F, acc[mi][ni][r]);
                else        cp[(size_t)r * OUT_F] = acc[mi][ni][r];
            }
        }
}

extern "C" void kernel_launch(void* const* d_in, const int* in_sizes, int n_in,
                              void* d_out, int out_size, void* d_ws, size_t ws_size,
                              hipStream_t stream) {
    const float* x    = (const float*)d_in[0];
    const float* bw   = (const float*)d_in[1];
    const float* sw   = (const float*)d_in[2];
    const float* ss   = (const float*)d_in[3];

    const size_t wc_bytes   = (size_t)OUT_F * KC * 2;          // 18,874,368
    const size_t a_bytes    = (size_t)BATCH * KC * 2;          // 75,497,472
    const size_t part_bytes = 3ull * BATCH * OUT_F * 4;        // 50,331,648
    if (ws_size < wc_bytes + a_bytes) return;

    __bf16* Wc = (__bf16*)d_ws;
    __bf16* A  = (__bf16*)((char*)d_ws + wc_bytes);
    float*  P  = (float*)((char*)d_ws + wc_bytes + a_bytes);

    {   // Wc: 131072 + 1048576 threads
        const int total = OUT_F * IN_F / 8 + OUT_F * IN_F;
        prep_wc<<<(total + 255) / 256, 256, 0, stream>>>(bw, sw, ss, Wc);
    }
    {   // A: 524288 + 4194304 threads
        const int total = BATCH * IN_F / 8 + BATCH * IN_F;
        prep_a<<<(total + 255) / 256, 256, 0, stream>>>(x, A);
    }

    const int grid = (BATCH / BM) * (OUT_F / BN) * SPLITK;     // 256
    if (ws_size >= wc_bytes + a_bytes + part_bytes) {
        // store path: ks0 -> d_out, ks1-3 -> partials; then reduce
        kan_gemm<false><<<grid, 512, 0, stream>>>(A, Wc, (float*)d_out, P);
        reduce_k<<<2048, 256, 0, stream>>>((float4*)d_out, (const float4*)P);
    } else {
        // fallback: r6 atomic path
        const int n4 = BATCH * OUT_F / 4;
        zero_out<<<n4 / 256, 256, 0, stream>>>((float4*)d_out, n4);
        kan_gemm<true><<<grid, 512, 0, stream>>>(A, Wc, (float*)d_out, P);
    }
}

// Round 8
// 117.234 us; speedup vs baseline: 1.4394x; 1.0118x over previous
//
#include <hip/hip_runtime.h>
#include <hip/hip_bf16.h>

// ---- problem constants -------------------------------------------------
#define IN_F   1024
#define OUT_F  1024
#define GS     5          // grid_size
#define SO     3          // spline_order
#define NB     (GS + SO)  // 8 basis functions per feature
#define NG     (GS + 2*SO + 1) // 12 grid points per feature row
#define BATCH  4096
#define KC     (IN_F + IN_F * NB)   // 9216 combined-K
#define BM 256
#define BN 256
#define BK 64
#define SPLITK 4
#define KPART  (KC / SPLITK)   // 2304
#define NT     (KPART / BK)    // 36 K-tiles per block

typedef __bf16 bf16x8 __attribute__((ext_vector_type(8)));
typedef float  f32x4  __attribute__((ext_vector_type(4)));

__device__ __forceinline__ void gload_lds16(const void* g, void* l) {
    __builtin_amdgcn_global_load_lds(
        (const __attribute__((address_space(1))) void*)g,
        (__attribute__((address_space(3))) void*)l,
        16, 0, 0);
}

// ---- fused prep: blocks [0,WC_BLK) build Wc, rest build A ---------------
#define WC_BLK 4608   // (131072 + 1048576) / 256
#define A_BLK  18432  // (524288 + 4194304) / 256

__global__ __launch_bounds__(256) void prep_all(const float* __restrict__ bw,
                                                const float* __restrict__ sw,
                                                const float* __restrict__ ss,
                                                const float* __restrict__ x,
                                                __bf16* __restrict__ W,
                                                __bf16* __restrict__ A) {
    if (blockIdx.x < WC_BLK) {
        const int t = blockIdx.x * 256 + threadIdx.x;
        const int NBASE = OUT_F * IN_F / 8;      // 131072 threads, 8 elems each
        if (t < NBASE) {
            const int o  = t >> 7;
            const int c8 = (t & 127) * 8;
            const float4* sp = (const float4*)(bw + (size_t)o * IN_F + c8);
            float4 v0 = sp[0], v1 = sp[1];
            float v[8] = {v0.x, v0.y, v0.z, v0.w, v1.x, v1.y, v1.z, v1.w};
            bf16x8 ov;
#pragma unroll
            for (int j = 0; j < 8; ++j) ov[j] = (__bf16)v[j];
            *(bf16x8*)(W + (size_t)o * KC + c8) = ov;
        } else {
            const int u = t - NBASE;             // one (o,f) pair per thread
            if (u >= OUT_F * IN_F) return;
            const int o = u >> 10, f = u & 1023;
            const float s = ss[(size_t)o * IN_F + f];
            const float4* sp = (const float4*)(sw + ((size_t)o * IN_F + f) * NB);
            float4 v0 = sp[0], v1 = sp[1];
            float v[8] = {v0.x, v0.y, v0.z, v0.w, v1.x, v1.y, v1.z, v1.w};
            bf16x8 ov;
#pragma unroll
            for (int j = 0; j < 8; ++j) ov[j] = (__bf16)(v[j] * s);
            *(bf16x8*)(W + (size_t)o * KC + IN_F + (size_t)f * NB) = ov;
        }
    } else {
        const int t = (blockIdx.x - WC_BLK) * 256 + threadIdx.x;
        const int NBASE = BATCH * IN_F / 8;      // silu: 8 elems/thread
        if (t < NBASE) {
            const int b  = t >> 7;
            const int c8 = (t & 127) * 8;
            const float4* sp = (const float4*)(x + (size_t)b * IN_F + c8);
            float4 v0 = sp[0], v1 = sp[1];
            float v[8] = {v0.x, v0.y, v0.z, v0.w, v1.x, v1.y, v1.z, v1.w};
            bf16x8 ov;
#pragma unroll
            for (int j = 0; j < 8; ++j) {
                float xx = v[j];
                ov[j] = (__bf16)(xx / (1.0f + __expf(-xx)));
            }
            *(bf16x8*)(A + (size_t)b * KC + c8) = ov;
        } else {
            const int u = t - NBASE;             // one (b,f) pair per thread
            if (u >= BATCH * IN_F) return;
            const int b = u >> 10, f = u & 1023;
            const float xv = x[(size_t)b * IN_F + f];
            const float h = 2.0f / GS;           // 0.4; uniform grid
            float gv[NG];
#pragma unroll
            for (int j = 0; j < NG; ++j) gv[j] = (float)(j - SO) * h - 1.0f;
            float bas[NB + SO];                  // 11 order-0 bases
#pragma unroll
            for (int j = 0; j < NB + SO; ++j)
                bas[j] = (xv >= gv[j] && xv < gv[j + 1]) ? 1.0f : 0.0f;
#pragma unroll
            for (int k = 1; k <= SO; ++k) {
                const float rk = 1.0f / ((float)k * h);   // constant-folded
#pragma unroll
                for (int j = 0; j <= (NB + SO - 1) - k; ++j) {
                    float left  = (xv - gv[j]) * rk;
                    float right = (gv[j + k + 1] - xv) * rk;
                    bas[j] = left * bas[j] + right * bas[j + 1];
                }
            }
            bf16x8 ov;
#pragma unroll
            for (int i = 0; i < NB; ++i) ov[i] = (__bf16)bas[i];
            *(bf16x8*)(A + (size_t)b * KC + IN_F + (size_t)f * NB) = ov;
        }
    }
}

// ---- zero-fill d_out (atomic-fallback path only) -----------------------
__global__ __launch_bounds__(256) void zero_out(float4* __restrict__ p, int n4) {
    const int i = blockIdx.x * 256 + threadIdx.x;
    if (i < n4) p[i] = float4{0.f, 0.f, 0.f, 0.f};
}

// ---- sum split-K partials into d_out (ks=0 wrote d_out directly) -------
__global__ __launch_bounds__(256) void reduce_k(float4* __restrict__ C,
                                                const float4* __restrict__ P) {
    const size_t n4 = (size_t)BATCH * OUT_F / 4;   // 1,048,576
    for (size_t i = blockIdx.x * 256 + threadIdx.x; i < n4; i += 2048 * 256) {
        float4 c  = C[i];
        float4 p0 = P[i];
        float4 p1 = P[n4 + i];
        float4 p2 = P[2 * n4 + i];
        c.x += p0.x + p1.x + p2.x;
        c.y += p0.y + p1.y + p2.y;
        c.z += p0.z + p1.z + p2.z;
        c.w += p0.w + p1.w + p2.w;
        C[i] = c;
    }
}

// ---- m201-style 4-phase/K-tile 256x256 GEMM, split-K -------------------
// r8 change: DISJOINT A-fragment register sets a0/a1 so every ds_read's
// destination regs have WAR distance >= 2 MFMA clusters from their last
// consumer (m201's quadrant cycle). Read/consume cycle:
//   Ph1 rd{a0,b01} | Q1 a0*b01 | Ph2 rd{b23} | Q2 a0*b23 |
//   Ph3 rd{a1}     | Q3 a1*b01 | Ph4 stage   | Q4 a1*b23
#define PH_SYNC do { __builtin_amdgcn_s_barrier();                            \
    asm volatile("s_waitcnt lgkmcnt(0)" ::: "memory");                        \
    __builtin_amdgcn_sched_barrier(0); } while (0)

#define MFMA16(AF, BF, MI0, NI0)                                              \
    __builtin_amdgcn_s_setprio(1);                                            \
    _Pragma("unroll")                                                         \
    for (int kk_ = 0; kk_ < 2; ++kk_)                                         \
        _Pragma("unroll")                                                     \
        for (int i_ = 0; i_ < 4; ++i_)                                        \
            _Pragma("unroll")                                                 \
            for (int n_ = 0; n_ < 2; ++n_)                                    \
                acc[(MI0) + i_][(NI0) + n_] =                                 \
                    __builtin_amdgcn_mfma_f32_16x16x32_bf16(                  \
                        AF[i_][kk_], BF[n_][kk_],                             \
                        acc[(MI0) + i_][(NI0) + n_], 0, 0, 0);                \
    __builtin_amdgcn_s_setprio(0);                                            \
    __builtin_amdgcn_s_barrier();

#define RD_A4(DST, LBUF, MI0)                                                 \
    _Pragma("unroll")                                                         \
    for (int i_ = 0; i_ < 4; ++i_) {                                          \
        DST[i_][0] = *(const bf16x8*)&(LBUF)[((MI0) + i_) * 1024 + aRow + slot0]; \
        DST[i_][1] = *(const bf16x8*)&(LBUF)[((MI0) + i_) * 1024 + aRow + slot1]; \
    }

#define RD_B2(DST, LBUF, NI0)                                                 \
    _Pragma("unroll")                                                         \
    for (int n_ = 0; n_ < 2; ++n_) {                                          \
        DST[n_][0] = *(const bf16x8*)&(LBUF)[bRow + ((NI0) + n_) * 1024 + slot0]; \
        DST[n_][1] = *(const bf16x8*)&(LBUF)[bRow + ((NI0) + n_) * 1024 + slot1]; \
    }

template<bool ATOMIC>
__global__ __launch_bounds__(512, 2) void kan_gemm(const __bf16* __restrict__ A,
                                                   const __bf16* __restrict__ W,
                                                   float* __restrict__ C,
                                                   float* __restrict__ P) {
    __shared__ __bf16 sA[2][2][128 * BK];   // [buf][half][128x64] = 64 KiB
    __shared__ __bf16 sB[2][2][128 * BK];   // 64 KiB

    const int tid  = threadIdx.x;
    const int gid  = blockIdx.x;
    // bijective XCD swizzle (256 = 8*32): XCD x owns one ks, two bn panels.
    const int work = (gid & 7) * 32 + (gid >> 3);
    const int ks = work >> 6;          // 0..3
    const int bn = (work >> 4) & 3;    // 0..3
    const int bm = work & 15;          // 0..15

    const int lane = tid & 63;
    const int wv   = tid >> 6;         // 0..7
    const int wm   = wv >> 2;          // 0..1: A half
    const int wn   = wv & 3;           // 0..3: B half = wn>>1, sub = wn&1
    const int lr   = lane & 15;        // fragment row
    const int hi   = lane >> 4;        // 0..3: k-subslot
    const int key  = lr & 7;           // swizzle key (frag rows = 16*m + lr)

    const int slot0 = ((hi ^ key) << 3);        // kk=0: 16B slot 0..3
    const int slot1 = (((4 + hi) ^ key) << 3);  // kk=1: slot 4..7
    const int aRow  = lr * 64;                  // within sA[b][wm]
    const int bRow  = ((wn & 1) * 64 + lr) * 64;// within sB[b][wn>>1]

    // staging map: thread -> (row, swizzled col) for each half-tile
    const int srow = tid >> 3;                       // 0..63
    const int scol = ((tid & 7) ^ (srow & 7)) << 3;  // elems

    const __bf16* gA = A + (size_t)(bm * BM) * KC + ks * KPART;
    const __bf16* gW = W + (size_t)(bn * BN) * KC + ks * KPART;

    f32x4 acc[8][4] = {};
    bf16x8 a0[4][2], a1[4][2], b01[2][2], b23[2][2];

    auto stageA = [&](int buf, int h, int kt) {      // one 16 KiB half-tile
#pragma unroll
        for (int l = 0; l < 2; ++l)
            gload_lds16(gA + (size_t)(h * 128 + l * 64 + srow) * KC + kt * BK + scol,
                        &sA[buf][h][(l * 512 + tid) * 8]);
    };
    auto stageB = [&](int buf, int h, int kt) {
#pragma unroll
        for (int l = 0; l < 2; ++l)
            gload_lds16(gW + (size_t)(h * 128 + l * 64 + srow) * KC + kt * BK + scol,
                        &sB[buf][h][(l * 512 + tid) * 8]);
    };

    // prologue: tile0 fully (8 loads) + tile1 A0,A1,B0 (6 loads)
    stageA(0, 0, 0); stageA(0, 1, 0); stageB(0, 0, 0); stageB(0, 1, 0);
    stageA(1, 0, 1); stageA(1, 1, 1); stageB(1, 0, 1);
    asm volatile("s_waitcnt vmcnt(6)\n\ts_barrier" ::: "memory");

    for (int kt = 0; kt < NT; ++kt) {
        const int b = kt & 1;
        const __bf16* LA = &sA[b][wm][0];
        const __bf16* LB = &sB[b][wn >> 1][0];

        // ---- Ph1: read a0 (8) + b01 (4); MFMA Q1
        // (a0 last consumed by prev-tile Q2: 2 clusters back; b01 by Q3)
        RD_A4(a0, LA, 0);
        RD_B2(b01, LB, 0);
        PH_SYNC;
        MFMA16(a0, b01, 0, 0);

        // ---- Ph2: read b23 (4); stage (kt+1).B1; MFMA Q2
        // (b23 last consumed by prev-tile Q4: 2 clusters back)
        RD_B2(b23, LB, 2);
        if (kt + 1 < NT) stageB(b ^ 1, 1, kt + 1);
        PH_SYNC;
        MFMA16(a0, b23, 0, 2);

        // ---- Ph3: read a1 (8); stage (kt+2).B0; MFMA Q3
        // (a1 last consumed by prev-tile Q4: 3 clusters back)
        RD_A4(a1, LA, 4);
        if (kt + 2 < NT) stageB(b, 0, kt + 2);
        PH_SYNC;
        MFMA16(a1, b01, 4, 0);

        // ---- Ph4: stage (kt+2).A0,A1; MFMA Q4
        if (kt + 2 < NT) { stageA(b, 0, kt + 2); stageA(b, 1, kt + 2); }
        __builtin_amdgcn_s_barrier();
        __builtin_amdgcn_s_setprio(1);
#pragma unroll
        for (int kk_ = 0; kk_ < 2; ++kk_)
#pragma unroll
            for (int i_ = 0; i_ < 4; ++i_)
#pragma unroll
                for (int n_ = 0; n_ < 2; ++n_)
                    acc[4 + i_][2 + n_] = __builtin_amdgcn_mfma_f32_16x16x32_bf16(
                        a1[i_][kk_], b23[n_][kk_], acc[4 + i_][2 + n_], 0, 0, 0);
        __builtin_amdgcn_s_setprio(0);

        // ---- boundary: counted wait (tile kt+2's loads stay in flight)
        if (kt + 2 < NT)
            asm volatile("s_waitcnt vmcnt(6)\n\ts_barrier" ::: "memory");
        else if (kt + 1 < NT)
            asm volatile("s_waitcnt vmcnt(0)\n\ts_barrier" ::: "memory");
    }

    // epilogue: C/D layout col=lane&15, row=hi*4+reg
    const int cr = hi * 4, cc = lane & 15;
    float* dst;
    if (ATOMIC) dst = C;
    else        dst = (ks == 0) ? C : P + (size_t)(ks - 1) * BATCH * OUT_F;
#pragma unroll
    for (int mi = 0; mi < 8; ++mi)
#pragma unroll
        for (int ni = 0; ni < 4; ++ni) {
            float* cp = dst + (size_t)(bm * BM + wm * 128 + mi * 16 + cr) * OUT_F
                            + bn * BN + wn * 64 + ni * 16 + cc;
#pragma unroll
            for (int r = 0; r < 4; ++r) {
                if (ATOMIC) unsafeAtomicAdd(cp + (size_t)r * OUT_F, acc[mi][ni][r]);
                else        cp[(size_t)r * OUT_F] = acc[mi][ni][r];
            }
        }
}

extern "C" void kernel_launch(void* const* d_in, const int* in_sizes, int n_in,
                              void* d_out, int out_size, void* d_ws, size_t ws_size,
                              hipStream_t stream) {
    const float* x    = (const float*)d_in[0];
    const float* bw   = (const float*)d_in[1];
    const float* sw   = (const float*)d_in[2];
    const float* ss   = (const float*)d_in[3];

    const size_t wc_bytes   = (size_t)OUT_F * KC * 2;          // 18,874,368
    const size_t a_bytes    = (size_t)BATCH * KC * 2;          // 75,497,472
    const size_t part_bytes = 3ull * BATCH * OUT_F * 4;        // 50,331,648
    if (ws_size < wc_bytes + a_bytes) return;

    __bf16* Wc = (__bf16*)d_ws;
    __bf16* A  = (__bf16*)((char*)d_ws + wc_bytes);
    float*  P  = (float*)((char*)d_ws + wc_bytes + a_bytes);

    prep_all<<<WC_BLK + A_BLK, 256, 0, stream>>>(bw, sw, ss, x, Wc, A);

    const int grid = (BATCH / BM) * (OUT_F / BN) * SPLITK;     // 256
    if (ws_size >= wc_bytes + a_bytes + part_bytes) {
        // store path: ks0 -> d_out, ks1-3 -> partials; then reduce
        kan_gemm<false><<<grid, 512, 0, stream>>>(A, Wc, (float*)d_out, P);
        reduce_k<<<2048, 256, 0, stream>>>((float4*)d_out, (const float4*)P);
    } else {
        // fallback: atomic path
        const int n4 = BATCH * OUT_F / 4;
        zero_out<<<n4 / 256, 256, 0, stream>>>((float4*)d_out, n4);
        kan_gemm<true><<<grid, 512, 0, stream>>>(A, Wc, (float*)d_out, P);
    }
}